// Round 1
// baseline (13964.282 us; speedup 1.0000x reference)
//
#include <hip/hip_runtime.h>

typedef _Float16 half8 __attribute__((ext_vector_type(8)));
typedef float f32x4 __attribute__((ext_vector_type(4)));

#define TT 512
#define HH 512

struct ScanParams {
  const float* W[8];     // W_i,W_f,W_c,W_o, Wb_i,Wb_f,Wb_c,Wb_o   [D][H]
  const float* U[8];     // U_i,...,Ub_o                           [H][H]
  const float* bias[8];  // b_i,...,bb_o                           [H]
  const _Float16* x16;   // [B][T][D] f16
  _Float16* hbuf;        // [2 dir][2 parity][32 b][512 u] f16
  int* flags;            // [2 dir][512 step][64 wg]
  _Float16* hs_b;        // [512 s][32 b][512 u] f16 (backward h)
  float* out;            // [B][T][H] f32 (forward writes directly)
};

__global__ void convert_x_kernel(const float* __restrict__ x, _Float16* __restrict__ x16) {
  const size_t i = ((size_t)blockIdx.x * blockDim.x + threadIdx.x) * 8;
  float4 v0 = *(const float4*)(x + i);
  float4 v1 = *(const float4*)(x + i + 4);
  half8 h;
  h[0] = (_Float16)v0.x; h[1] = (_Float16)v0.y; h[2] = (_Float16)v0.z; h[3] = (_Float16)v0.w;
  h[4] = (_Float16)v1.x; h[5] = (_Float16)v1.y; h[6] = (_Float16)v1.z; h[7] = (_Float16)v1.w;
  *(half8*)(x16 + i) = h;
}

__global__ void zero_kernel(int* __restrict__ p) {
  p[(size_t)blockIdx.x * blockDim.x + threadIdx.x] = 0;
}

__device__ __forceinline__ float hsig(float x) {
  return fminf(fmaxf(fmaf(x, 0.2f, 0.5f), 0.0f), 1.0f);
}

// 128 WGs x 256 threads (cooperative). WG = (dir d = bid>>6, slice j = bid&63).
// WG owns units u in [j*8, j*8+8), all 4 gates -> 32 output cols of z = x@W + h@U.
// Wave w: n-tile nt = w&1 (16 cols), k-half kh = w>>1 (256 of the 512 K).
// Col n (0..15) of a wave <-> gate g = n&3, unit u = j*8 + nt*4 + (n>>2).
// U/W B-fragments resident in VGPRs for the whole kernel.
__global__ __launch_bounds__(256, 1) void lstm_scan_kernel(ScanParams p) {
  const int tid = threadIdx.x;
  const int bid = blockIdx.x;
  const int d   = bid >> 6;
  const int j   = bid & 63;
  const int w   = tid >> 6;
  const int l   = tid & 63;
  const int r15 = l & 15;    // A-row (batch) / B-col index
  const int kg  = l >> 4;    // k-group 0..3 (8 consecutive k each)
  const int nt  = w & 1;
  const int kh  = w >> 1;
  const int g_l = r15 & 3;
  const int u_l = j * 8 + nt * 4 + (r15 >> 2);

  const float* __restrict__ Ug = p.U[4 * d + g_l];
  const float* __restrict__ Wg = p.W[4 * d + g_l];

  // Resident B-fragments: 8 k-tiles (this wave's k-half), 8 f16 each.
  half8 uf[8], wf[8];
#pragma unroll
  for (int kt = 0; kt < 8; ++kt) {
    half8 uv, wv;
#pragma unroll
    for (int jj = 0; jj < 8; ++jj) {
      const int k = (kh * 8 + kt) * 32 + kg * 8 + jj;
      uv[jj] = (_Float16)Ug[k * HH + u_l];
      wv[jj] = (_Float16)Wg[k * HH + u_l];
    }
    uf[kt] = uv; wf[kt] = wv;
  }

  // Elementwise identity: thread -> (batch b_e, local unit uu_e).
  const int b_e  = tid & 31;
  const int uu_e = tid >> 5;                       // 0..7
  const int u_e  = j * 8 + uu_e;
  const int slot_e = (uu_e >> 2) * 16 + (uu_e & 3) * 4;
  f32x4 biasv;
#pragma unroll
  for (int g = 0; g < 4; ++g) biasv[g] = p.bias[4 * d + g][u_e];

  __shared__ __align__(16) float zlds[2 * 32 * 36];  // [k-half][b][32 cols + pad]

  const _Float16* __restrict__ x16 = p.x16;
  _Float16* hbuf = p.hbuf;
  int* flags = p.flags;

  float c = 0.0f;

  for (int s = 0; s < TT; ++s) {
    const int t = d ? (TT - 1 - s) : s;

    f32x4 a0e = {0,0,0,0}, a0o = {0,0,0,0}, a1e = {0,0,0,0}, a1o = {0,0,0,0};

    // x_t @ W  (does not depend on the barrier -> overlaps waiting)
    const size_t xb0 = ((size_t)r15 * TT + t) * HH;
    const size_t xb1 = ((size_t)(r15 + 16) * TT + t) * HH;
#pragma unroll
    for (int kt = 0; kt < 8; ++kt) {
      const int dd = (kh * 8 + kt) * 32 + kg * 8;
      half8 a0 = *(const half8*)(x16 + xb0 + dd);
      half8 a1 = *(const half8*)(x16 + xb1 + dd);
      if (kt & 1) {
        a0o = __builtin_amdgcn_mfma_f32_16x16x32_f16(a0, wf[kt], a0o, 0, 0, 0);
        a1o = __builtin_amdgcn_mfma_f32_16x16x32_f16(a1, wf[kt], a1o, 0, 0, 0);
      } else {
        a0e = __builtin_amdgcn_mfma_f32_16x16x32_f16(a0, wf[kt], a0e, 0, 0, 0);
        a1e = __builtin_amdgcn_mfma_f32_16x16x32_f16(a1, wf[kt], a1e, 0, 0, 0);
      }
    }

    // Wait for all 64 WGs of this direction to publish step s-1's h.
    if (s > 0) {
      if (tid < 64) {
        const int* fl = flags + ((size_t)d * TT + (s - 1)) * 64 + tid;
        while (__hip_atomic_load(fl, __ATOMIC_ACQUIRE, __HIP_MEMORY_SCOPE_AGENT) == 0) {}
      }
      __syncthreads();
      __threadfence();  // invalidate L1 before reading other WGs' h
    }

    // h_{s} @ U  (read parity s&1; step 0 reads zeroed buffer)
    const _Float16* hb = hbuf + ((size_t)(d * 2 + (s & 1))) * (32 * HH);
#pragma unroll
    for (int kt = 0; kt < 8; ++kt) {
      const int dd = (kh * 8 + kt) * 32 + kg * 8;
      half8 a0 = *(const half8*)(hb + r15 * HH + dd);
      half8 a1 = *(const half8*)(hb + (r15 + 16) * HH + dd);
      if (kt & 1) {
        a0o = __builtin_amdgcn_mfma_f32_16x16x32_f16(a0, uf[kt], a0o, 0, 0, 0);
        a1o = __builtin_amdgcn_mfma_f32_16x16x32_f16(a1, uf[kt], a1o, 0, 0, 0);
      } else {
        a0e = __builtin_amdgcn_mfma_f32_16x16x32_f16(a0, uf[kt], a0e, 0, 0, 0);
        a1e = __builtin_amdgcn_mfma_f32_16x16x32_f16(a1, uf[kt], a1e, 0, 0, 0);
      }
    }
    const f32x4 acc0 = a0e + a0o;
    const f32x4 acc1 = a1e + a1o;

    // z -> LDS. D-frag: col = l&15, row = kg*4 + i  (m89-verified layout).
#pragma unroll
    for (int i = 0; i < 4; ++i) {
      zlds[(kh * 32 + kg * 4 + i) * 36 + nt * 16 + r15]      = acc0[i];
      zlds[(kh * 32 + 16 + kg * 4 + i) * 36 + nt * 16 + r15] = acc1[i];
    }
    __syncthreads();

    // Elementwise LSTM cell (k-halves summed here).
    f32x4 z = *(const f32x4*)&zlds[(size_t)b_e * 36 + slot_e]
            + *(const f32x4*)&zlds[(size_t)(32 + b_e) * 36 + slot_e];
    f32x4 pre = z + biasv;
    const float ig = hsig(pre[0]);
    const float fg = hsig(pre[1]);
    const float gg = tanhf(pre[2]);
    const float og = hsig(pre[3]);
    c = fg * c + ig * gg;
    const float h = og * tanhf(c);

    _Float16* hbw = hbuf + ((size_t)(d * 2 + ((s & 1) ^ 1))) * (32 * HH);
    hbw[b_e * HH + u_e] = (_Float16)h;
    if (d == 0) {
      p.out[((size_t)b_e * TT + t) * HH + u_e] = h;          // forward: straight to out
    } else {
      p.hs_b[((size_t)s * 32 + b_e) * HH + u_e] = (_Float16)h;
    }

    // Publish this step's h slice.
    __threadfence();
    __syncthreads();
    if (tid == 0) {
      __hip_atomic_store(flags + ((size_t)d * TT + s) * 64 + j, 1,
                         __ATOMIC_RELEASE, __HIP_MEMORY_SCOPE_AGENT);
    }
  }
}

__global__ void add_bwd_kernel(const _Float16* __restrict__ hs_b, float* __restrict__ out) {
  const size_t o = ((size_t)blockIdx.x * blockDim.x + threadIdx.x) * 8;
  const int u = (int)(o & (HH - 1));
  const int t = (int)((o >> 9) & (TT - 1));
  const int b = (int)(o >> 18);
  half8 hb = *(const half8*)(hs_b + ((size_t)t * 32 + b) * HH + u);
  float4 r0 = *(const float4*)(out + o);
  float4 r1 = *(const float4*)(out + o + 4);
  r0.x += (float)hb[0]; r0.y += (float)hb[1]; r0.z += (float)hb[2]; r0.w += (float)hb[3];
  r1.x += (float)hb[4]; r1.y += (float)hb[5]; r1.z += (float)hb[6]; r1.w += (float)hb[7];
  *(float4*)(out + o) = r0;
  *(float4*)(out + o + 4) = r1;
}

extern "C" void kernel_launch(void* const* d_in, const int* in_sizes, int n_in,
                              void* d_out, int out_size, void* d_ws, size_t ws_size,
                              hipStream_t stream) {
  (void)in_sizes; (void)n_in; (void)out_size; (void)ws_size;
  char* ws = (char*)d_ws;
  // ws layout (bytes):
  //   [0, 16777216)            x16   : 8.4M f16
  //   [16777216, 33554432)     hs_b  : 8.4M f16
  //   [33554432, 33685504)     hbuf  : 65536 f16
  //   [33685504, 33947648)     flags : 65536 int
  _Float16* x16  = (_Float16*)ws;
  _Float16* hs_b = (_Float16*)(ws + 16777216);
  _Float16* hbuf = (_Float16*)(ws + 33554432);
  int*      flags = (int*)(ws + 33685504);

  convert_x_kernel<<<4096, 256, 0, stream>>>((const float*)d_in[0], x16);
  zero_kernel<<<384, 256, 0, stream>>>((int*)(ws + 33554432));  // hbuf + flags (393216 B)

  ScanParams p;
  for (int g = 0; g < 8; ++g) {
    p.W[g]    = (const float*)d_in[1 + g];
    p.U[g]    = (const float*)d_in[9 + g];
    p.bias[g] = (const float*)d_in[17 + g];
  }
  p.x16 = x16; p.hbuf = hbuf; p.flags = flags; p.hs_b = hs_b; p.out = (float*)d_out;

  void* args[] = { (void*)&p };
  hipLaunchCooperativeKernel((const void*)lstm_scan_kernel, dim3(128), dim3(256),
                             args, 0, stream);

  add_bwd_kernel<<<4096, 256, 0, stream>>>(hs_b, (float*)d_out);
}

// Round 2
// 3629.302 us; speedup vs baseline: 3.8476x; 3.8476x over previous
//
#include <hip/hip_runtime.h>

typedef _Float16 half8 __attribute__((ext_vector_type(8)));
typedef float f32x4 __attribute__((ext_vector_type(4)));

#define TT 512
#define HH 512

// ws layout (bytes):
//   [0,          16777216)   x16     : [32][512][512] f16
//   [16777216,   50331648)   h_steps : [2 dir][512 step][32 b][512 u] f16
//   [50331648,   50397184)   hz      : [2][32][512] f16 zeros (h state 0)
//   [50397184,   50659328)   flags   : [2][512][64] int
//   [50659328,   54853632)   Upk     : packed U frags f16
//   [54853632,   59047936)   Wpk     : packed W frags f16
#define OFF_HSTEPS 16777216
#define OFF_HZ     50331648
#define OFF_FLAGS  50397184
#define OFF_UPK    50659328
#define OFF_WPK    54853632

struct ScanParams {
  const float* bias[8];
  const _Float16* x16;
  _Float16* h_steps;
  const _Float16* hz;
  int* flags;
  const _Float16* Upk;
  const _Float16* Wpk;
  float* out;
};

struct PackParams {
  const float* U[8];
  const float* W[8];
  _Float16* Upk;
  _Float16* Wpk;
};

__global__ void convert_x_kernel(const float* __restrict__ x, _Float16* __restrict__ x16) {
  const size_t i = ((size_t)blockIdx.x * blockDim.x + threadIdx.x) * 8;
  float4 v0 = *(const float4*)(x + i);
  float4 v1 = *(const float4*)(x + i + 4);
  half8 h;
  h[0] = (_Float16)v0.x; h[1] = (_Float16)v0.y; h[2] = (_Float16)v0.z; h[3] = (_Float16)v0.w;
  h[4] = (_Float16)v1.x; h[5] = (_Float16)v1.y; h[6] = (_Float16)v1.z; h[7] = (_Float16)v1.w;
  *(half8*)(x16 + i) = h;
}

// Pack U/W into exact MFMA B-fragment order:
// idx = ((((d*64 + j)*2 + ct)*16 + kt)*64 + l)*8 + jj
// lane l: r15=l&15 (col), kg=l>>4; col -> gate g=r15&3, unit u=j*8+ct*4+(r15>>2);
// k = kt*32 + kg*8 + jj.  Value = M[4d+g][k*512 + u].
__global__ void pack_frags_kernel(PackParams p) {
  const unsigned n = blockIdx.x * 256 + threadIdx.x;   // 2 * 2^21 total
  const unsigned o = n & 2097151u;
  const int sel = n >> 21;                              // 0 = U, 1 = W
  const int jj = o & 7, l = (o >> 3) & 63, kt = (o >> 9) & 15;
  const int ct = (o >> 13) & 1, j = (o >> 14) & 63, d = (o >> 20) & 1;
  const int r15 = l & 15, kg = l >> 4;
  const int g = r15 & 3;
  const int u = j * 8 + ct * 4 + (r15 >> 2);
  const int k = kt * 32 + kg * 8 + jj;
  const float* M = sel ? p.W[4 * d + g] : p.U[4 * d + g];
  _Float16* dst = sel ? p.Wpk : p.Upk;
  dst[o] = (_Float16)M[k * HH + u];
}

__global__ void zero_kernel(int* __restrict__ p) {
  p[(size_t)blockIdx.x * blockDim.x + threadIdx.x] = 0;
}

__device__ __forceinline__ float hsig(float x) {
  return fminf(fmaxf(fmaf(x, 0.2f, 0.5f), 0.0f), 1.0f);
}

// 128 WGs x 256 thr (cooperative). WG = (d = bid>>6, j = bid&63) owns units
// [j*8, j*8+8) x 4 gates = 32 cols. Wave w: rows rt=(w&1)*16..+16, cols
// ct=(w>>1)*16..+16, FULL K=512 (no k-split). U/W frags resident in VGPRs.
__global__ __launch_bounds__(256, 1) void lstm_scan_kernel(ScanParams p) {
  const int tid = threadIdx.x;
  const int bid = blockIdx.x;
  const int d   = bid >> 6;
  const int j   = bid & 63;
  const int w   = tid >> 6;
  const int l   = tid & 63;
  const int r15 = l & 15;
  const int kg  = l >> 4;
  const int rt  = w & 1;
  const int ct  = w >> 1;

  // Resident B-fragments (perfectly coalesced half8 loads from packed arrays).
  half8 uf[16], wf[16];
  {
    const half8* ub = (const half8*)p.Upk;
    const half8* wb = (const half8*)p.Wpk;
    const int base = (((d * 64 + j) * 2 + ct) * 16) * 64 + l;
#pragma unroll
    for (int kt = 0; kt < 16; ++kt) {
      uf[kt] = ub[base + kt * 64];
      wf[kt] = wb[base + kt * 64];
    }
  }

  // Elementwise identity: thread -> (batch b_e, local unit uu_e); u-major for
  // coalesced h stores (8 consecutive lanes -> 8 consecutive units = 16B).
  const int b_e  = tid >> 3;
  const int uu_e = tid & 7;
  const int u_e  = j * 8 + uu_e;
  const int slot_e = (uu_e >> 2) * 16 + (uu_e & 3) * 4;
  f32x4 biasv;
#pragma unroll
  for (int g = 0; g < 4; ++g) biasv[g] = p.bias[4 * d + g][u_e];

  __shared__ __align__(16) float zlds[32 * 36];

  const int arow = rt * 16 + r15;       // this lane's A row (batch)
  float c = 0.0f;

  for (int s = 0; s < TT; ++s) {
    const int t = d ? (TT - 1 - s) : s;

    f32x4 acc0 = {0,0,0,0}, acc1 = {0,0,0,0}, acc2 = {0,0,0,0}, acc3 = {0,0,0,0};

    // x_t @ W — independent of the flag wait; issued before polling.
    {
      const half8* xb = (const half8*)(p.x16 + ((size_t)arow * TT + t) * HH);
#pragma unroll
      for (int kt = 0; kt < 16; ++kt) {
        half8 a = xb[kt * 4 + kg];
        if ((kt & 3) == 0) acc0 = __builtin_amdgcn_mfma_f32_16x16x32_f16(a, wf[kt], acc0, 0, 0, 0);
        else if ((kt & 3) == 1) acc1 = __builtin_amdgcn_mfma_f32_16x16x32_f16(a, wf[kt], acc1, 0, 0, 0);
        else if ((kt & 3) == 2) acc2 = __builtin_amdgcn_mfma_f32_16x16x32_f16(a, wf[kt], acc2, 0, 0, 0);
        else                    acc3 = __builtin_amdgcn_mfma_f32_16x16x32_f16(a, wf[kt], acc3, 0, 0, 0);
      }
    }
    __builtin_amdgcn_sched_barrier(0);  // keep x-MFMAs issued before the poll

    // Wait for all 64 WGs of this direction to publish h(s).
    if (s > 0) {
      if (tid < 64) {
        const int* fl = p.flags + ((d * TT + (s - 1)) << 6) + tid;
        while (__hip_atomic_load(fl, __ATOMIC_RELAXED, __HIP_MEMORY_SCOPE_AGENT) == 0) {}
      }
      __syncthreads();
    }

    // h(s) @ U — plain cached loads (per-step buffer: written once, read once).
    {
      const _Float16* hbase = (s == 0)
          ? (p.hz + d * (32 * HH))
          : (p.h_steps + ((size_t)(d * TT + (s - 1))) * (32 * HH));
      const half8* hb = (const half8*)(hbase + arow * HH);
#pragma unroll
      for (int kt = 0; kt < 16; ++kt) {
        half8 a = hb[kt * 4 + kg];
        if ((kt & 3) == 0) acc0 = __builtin_amdgcn_mfma_f32_16x16x32_f16(a, uf[kt], acc0, 0, 0, 0);
        else if ((kt & 3) == 1) acc1 = __builtin_amdgcn_mfma_f32_16x16x32_f16(a, uf[kt], acc1, 0, 0, 0);
        else if ((kt & 3) == 2) acc2 = __builtin_amdgcn_mfma_f32_16x16x32_f16(a, uf[kt], acc2, 0, 0, 0);
        else                    acc3 = __builtin_amdgcn_mfma_f32_16x16x32_f16(a, uf[kt], acc3, 0, 0, 0);
      }
    }
    const f32x4 z = (acc0 + acc1) + (acc2 + acc3);

    // z -> LDS. D-frag: col = r15, row = kg*4 + i (m89-verified layout).
#pragma unroll
    for (int i = 0; i < 4; ++i)
      zlds[(rt * 16 + kg * 4 + i) * 36 + ct * 16 + r15] = z[i];
    __syncthreads();

    // Elementwise LSTM cell.
    f32x4 pre = *(const f32x4*)&zlds[(size_t)b_e * 36 + slot_e] + biasv;
    const float ig = hsig(pre[0]);
    const float fg = hsig(pre[1]);
    const float gg = tanhf(pre[2]);
    const float og = hsig(pre[3]);
    c = fg * c + ig * gg;
    const float h = og * tanhf(c);

    // Publish h: agent-scope relaxed store (sc1 write-through, no L2 dirtying).
    {
      const _Float16 h16 = (_Float16)h;
      const unsigned short hbits = __builtin_bit_cast(unsigned short, h16);
      unsigned short* hw = (unsigned short*)p.h_steps +
                           ((size_t)(d * TT + s)) * (32 * HH) + b_e * HH + u_e;
      __hip_atomic_store(hw, hbits, __ATOMIC_RELAXED, __HIP_MEMORY_SCOPE_AGENT);
      if (d == 0)
        p.out[((size_t)b_e * TT + s) * HH + u_e] = h;   // forward: t == s
    }

    asm volatile("s_waitcnt vmcnt(0)" ::: "memory");  // h stores at coherence point
    __syncthreads();                                   // all waves' stores drained
    if (tid == 0)
      __hip_atomic_store(p.flags + ((d * TT + s) << 6) + j, 1,
                         __ATOMIC_RELAXED, __HIP_MEMORY_SCOPE_AGENT);
  }
}

__global__ void add_bwd_kernel(const _Float16* __restrict__ h_steps, float* __restrict__ out) {
  const size_t o = ((size_t)blockIdx.x * blockDim.x + threadIdx.x) * 8;
  const int u = (int)(o & (HH - 1));
  const int t = (int)((o >> 9) & (TT - 1));
  const int b = (int)(o >> 18);
  // backward h for out position t is h_steps[1][t]
  half8 hb = *(const half8*)(h_steps + ((size_t)(TT + t)) * (32 * HH) + b * HH + u);
  float4 r0 = *(const float4*)(out + o);
  float4 r1 = *(const float4*)(out + o + 4);
  r0.x += (float)hb[0]; r0.y += (float)hb[1]; r0.z += (float)hb[2]; r0.w += (float)hb[3];
  r1.x += (float)hb[4]; r1.y += (float)hb[5]; r1.z += (float)hb[6]; r1.w += (float)hb[7];
  *(float4*)(out + o) = r0;
  *(float4*)(out + o + 4) = r1;
}

extern "C" void kernel_launch(void* const* d_in, const int* in_sizes, int n_in,
                              void* d_out, int out_size, void* d_ws, size_t ws_size,
                              hipStream_t stream) {
  (void)in_sizes; (void)n_in; (void)out_size; (void)ws_size;
  char* ws = (char*)d_ws;
  _Float16* x16     = (_Float16*)ws;
  _Float16* h_steps = (_Float16*)(ws + OFF_HSTEPS);
  _Float16* hz      = (_Float16*)(ws + OFF_HZ);
  int*      flags   = (int*)(ws + OFF_FLAGS);
  _Float16* Upk     = (_Float16*)(ws + OFF_UPK);
  _Float16* Wpk     = (_Float16*)(ws + OFF_WPK);

  convert_x_kernel<<<4096, 256, 0, stream>>>((const float*)d_in[0], x16);

  PackParams pp;
  for (int g = 0; g < 8; ++g) {
    pp.W[g] = (const float*)d_in[1 + g];
    pp.U[g] = (const float*)d_in[9 + g];
  }
  pp.Upk = Upk; pp.Wpk = Wpk;
  pack_frags_kernel<<<16384, 256, 0, stream>>>(pp);

  // zero hz + flags (contiguous 327680 B = 81920 ints)
  zero_kernel<<<320, 256, 0, stream>>>((int*)(ws + OFF_HZ));

  ScanParams p;
  for (int g = 0; g < 8; ++g) p.bias[g] = (const float*)d_in[17 + g];
  p.x16 = x16; p.h_steps = h_steps; p.hz = hz; p.flags = flags;
  p.Upk = Upk; p.Wpk = Wpk; p.out = (float*)d_out;

  void* args[] = { (void*)&p };
  hipLaunchCooperativeKernel((const void*)lstm_scan_kernel, dim3(128), dim3(256),
                             args, 0, stream);

  add_bwd_kernel<<<4096, 256, 0, stream>>>(h_steps, (float*)d_out);
}

// Round 3
// 2889.898 us; speedup vs baseline: 4.8321x; 1.2559x over previous
//
#include <hip/hip_runtime.h>

typedef _Float16 half8 __attribute__((ext_vector_type(8)));
typedef float f32x4 __attribute__((ext_vector_type(4)));

#define TT 512
#define HH 512

// ws layout (bytes):
//   [0,        16777216)  x16   : [32 b][512 t][512 d] f16
//   [16777216, 50331648)  h_pk  : [2 dir][512 step][64 j][32 b][8 u] f16
//   [50331648, 50335744)  flags : [2 dir][8 slot][64 wg] int (monotonic ring)
//   [50335744, 54530048)  Upk   : packed U frags f16 (2^21)
//   [54530048, 58724352)  Wpk   : packed W frags f16 (2^21)
#define OFF_HPK   16777216
#define OFF_FLAGS 50331648
#define OFF_UPK   50335744
#define OFF_WPK   54530048

struct ScanParams {
  const float* bias[8];
  const _Float16* x16;
  _Float16* h_pk;
  int* flags;
  const _Float16* Upk;
  const _Float16* Wpk;
  float* out;
};

struct PackParams {
  const float* U[8];
  const float* W[8];
  _Float16* Upk;
  _Float16* Wpk;
};

__global__ void convert_x_kernel(const float* __restrict__ x, _Float16* __restrict__ x16) {
  const size_t i = ((size_t)blockIdx.x * blockDim.x + threadIdx.x) * 8;
  float4 v0 = *(const float4*)(x + i);
  float4 v1 = *(const float4*)(x + i + 4);
  half8 h;
  h[0] = (_Float16)v0.x; h[1] = (_Float16)v0.y; h[2] = (_Float16)v0.z; h[3] = (_Float16)v0.w;
  h[4] = (_Float16)v1.x; h[5] = (_Float16)v1.y; h[6] = (_Float16)v1.z; h[7] = (_Float16)v1.w;
  *(half8*)(x16 + i) = h;
}

// Pack U/W into MFMA B-fragment order:
// idx = ((((d*64 + j)*2 + ct)*16 + kt)*64 + l)*8 + jj
// lane l: r15=l&15, kg=l>>4; col -> g=r15&3, u=j*8+ct*4+(r15>>2); k=kt*32+kg*8+jj.
__global__ void pack_frags_kernel(PackParams p) {
  const unsigned n = blockIdx.x * 256 + threadIdx.x;   // 2 * 2^21 total
  const unsigned o = n & 2097151u;
  const int sel = n >> 21;                              // 0 = U, 1 = W
  const int jj = o & 7, l = (o >> 3) & 63, kt = (o >> 9) & 15;
  const int ct = (o >> 13) & 1, j = (o >> 14) & 63, d = (o >> 20) & 1;
  const int r15 = l & 15, kg = l >> 4;
  const int g = r15 & 3;
  const int u = j * 8 + ct * 4 + (r15 >> 2);
  const int k = kt * 32 + kg * 8 + jj;
  const float* M = sel ? p.W[4 * d + g] : p.U[4 * d + g];
  _Float16* dst = sel ? p.Wpk : p.Upk;
  dst[o] = (_Float16)M[k * HH + u];
}

__global__ void zero_kernel(int* __restrict__ p) {
  p[(size_t)blockIdx.x * blockDim.x + threadIdx.x] = 0;
}

__device__ __forceinline__ float hsig(float x) {
  return fminf(fmaxf(fmaf(x, 0.2f, 0.5f), 0.0f), 1.0f);
}

// 128 WGs x 256 thr (cooperative). WG = (d = bid>>6, j = bid&63) owns units
// [j*8, j*8+8) x 4 gates = 32 cols. Wave w: rows rt=(w&1)*16, cols ct=(w>>1)*16,
// full K=512.
__global__ __launch_bounds__(256, 1) void lstm_scan_kernel(ScanParams p) {
  const int tid = threadIdx.x;
  const int bid = blockIdx.x;
  const int d   = bid >> 6;
  const int j   = bid & 63;
  const int w   = tid >> 6;
  const int l   = tid & 63;
  const int r15 = l & 15;
  const int kg  = l >> 4;
  const int rt  = w & 1;
  const int ct  = w >> 1;

  half8 uf[16], wf[16];
  {
    const half8* ub = (const half8*)p.Upk;
    const half8* wb = (const half8*)p.Wpk;
    const int base = (((d * 64 + j) * 2 + ct) * 16) * 64 + l;
#pragma unroll
    for (int kt = 0; kt < 16; ++kt) {
      uf[kt] = ub[base + kt * 64];
      wf[kt] = wb[base + kt * 64];
    }
  }

  const int b_e  = tid >> 3;
  const int uu_e = tid & 7;
  const int u_e  = j * 8 + uu_e;
  const int slot_e = (uu_e >> 2) * 16 + (uu_e & 3) * 4;
  f32x4 biasv;
#pragma unroll
  for (int g = 0; g < 4; ++g) biasv[g] = p.bias[4 * d + g][u_e];

  __shared__ __align__(16) float zlds[32 * 36];
  __shared__ __align__(16) unsigned short hlds[256];

  const int arow = rt * 16 + r15;
  float c = 0.0f;

  for (int s = 0; s < TT; ++s) {
    const int t = d ? (TT - 1 - s) : s;

    f32x4 acc0 = {0,0,0,0}, acc1 = {0,0,0,0}, acc2 = {0,0,0,0}, acc3 = {0,0,0,0};

    // x_t @ W — independent of the flag wait; issued before polling.
    {
      const half8* xb = (const half8*)(p.x16 + ((size_t)arow * TT + t) * HH);
#pragma unroll
      for (int kt = 0; kt < 16; ++kt) {
        half8 a = xb[kt * 4 + kg];
        if ((kt & 3) == 0)      acc0 = __builtin_amdgcn_mfma_f32_16x16x32_f16(a, wf[kt], acc0, 0, 0, 0);
        else if ((kt & 3) == 1) acc1 = __builtin_amdgcn_mfma_f32_16x16x32_f16(a, wf[kt], acc1, 0, 0, 0);
        else if ((kt & 3) == 2) acc2 = __builtin_amdgcn_mfma_f32_16x16x32_f16(a, wf[kt], acc2, 0, 0, 0);
        else                    acc3 = __builtin_amdgcn_mfma_f32_16x16x32_f16(a, wf[kt], acc3, 0, 0, 0);
      }
    }
    __builtin_amdgcn_sched_barrier(0);

    if (s > 0) {
      // Wait for all 64 WGs of this direction (monotonic epoch flags,
      // one coalesced 64-lane load per poll round).
      if (tid < 64) {
        const int* fl = p.flags + ((d * 8 + ((s - 1) & 7)) << 6) + tid;
        while (__hip_atomic_load(fl, __ATOMIC_RELAXED, __HIP_MEMORY_SCOPE_AGENT) < s) {
          __builtin_amdgcn_s_sleep(1);
        }
      }
      __syncthreads();

      // h(s-1) @ U — plain cached loads; layout [j'][b][8u], chunk j' = kt*4+kg.
      const half8* hb = (const half8*)(p.h_pk + ((size_t)(d * TT + (s - 1))) * (64 * 256));
#pragma unroll
      for (int kt = 0; kt < 16; ++kt) {
        half8 a = hb[(kt * 4 + kg) * 32 + arow];
        if ((kt & 3) == 0)      acc0 = __builtin_amdgcn_mfma_f32_16x16x32_f16(a, uf[kt], acc0, 0, 0, 0);
        else if ((kt & 3) == 1) acc1 = __builtin_amdgcn_mfma_f32_16x16x32_f16(a, uf[kt], acc1, 0, 0, 0);
        else if ((kt & 3) == 2) acc2 = __builtin_amdgcn_mfma_f32_16x16x32_f16(a, uf[kt], acc2, 0, 0, 0);
        else                    acc3 = __builtin_amdgcn_mfma_f32_16x16x32_f16(a, uf[kt], acc3, 0, 0, 0);
      }
    }
    const f32x4 z = (acc0 + acc1) + (acc2 + acc3);

    // z -> LDS. D-frag: col = r15, row = kg*4 + i.
#pragma unroll
    for (int i = 0; i < 4; ++i)
      zlds[(rt * 16 + kg * 4 + i) * 36 + ct * 16 + r15] = z[i];
    __syncthreads();

    // Elementwise LSTM cell.
    f32x4 pre = *(const f32x4*)&zlds[(size_t)b_e * 36 + slot_e] + biasv;
    const float ig = hsig(pre[0]);
    const float fg = hsig(pre[1]);
    const float gg = tanhf(pre[2]);
    const float og = hsig(pre[3]);
    c = fg * c + ig * gg;
    const float h = og * tanhf(c);

    const _Float16 h16 = (_Float16)h;
    hlds[tid] = __builtin_bit_cast(unsigned short, h16);
    if (d == 0)
      p.out[((size_t)b_e * TT + s) * HH + u_e] = h;   // forward: t == s
    __syncthreads();

    // Publish: wave 0 stores the WG's contiguous 512 B slice (64 x 8B atomics,
    // one coalesced wave op), drains, then lane 0 sets the epoch flag.
    if (tid < 64) {
      const unsigned long long v = ((const unsigned long long*)hlds)[tid];
      unsigned long long* dst = (unsigned long long*)p.h_pk +
                                ((size_t)(d * TT + s) * 64 + j) * 64 + tid;
      __hip_atomic_store(dst, v, __ATOMIC_RELAXED, __HIP_MEMORY_SCOPE_AGENT);
      asm volatile("s_waitcnt vmcnt(0)" ::: "memory");
      if (tid == 0)
        __hip_atomic_store(p.flags + ((d * 8 + (s & 7)) << 6) + j, s + 1,
                           __ATOMIC_RELAXED, __HIP_MEMORY_SCOPE_AGENT);
    }
  }
}

__global__ void add_bwd_kernel(const _Float16* __restrict__ h_pk, float* __restrict__ out) {
  const unsigned idx = blockIdx.x * 256 + threadIdx.x;   // 32*512*64
  const int j = idx & 63;
  const int t = (idx >> 6) & 511;
  const int b = idx >> 15;
  // backward h for out position t is h_pk[1][t][j][b][:]
  half8 hb = ((const half8*)h_pk)[((size_t)(TT + t) * 64 + j) * 32 + b];
  float* o = out + (((size_t)b * TT + t) * HH + j * 8);
  float4 r0 = *(const float4*)o;
  float4 r1 = *(const float4*)(o + 4);
  r0.x += (float)hb[0]; r0.y += (float)hb[1]; r0.z += (float)hb[2]; r0.w += (float)hb[3];
  r1.x += (float)hb[4]; r1.y += (float)hb[5]; r1.z += (float)hb[6]; r1.w += (float)hb[7];
  *(float4*)o = r0;
  *(float4*)(o + 4) = r1;
}

extern "C" void kernel_launch(void* const* d_in, const int* in_sizes, int n_in,
                              void* d_out, int out_size, void* d_ws, size_t ws_size,
                              hipStream_t stream) {
  (void)in_sizes; (void)n_in; (void)out_size; (void)ws_size;
  char* ws = (char*)d_ws;
  _Float16* x16   = (_Float16*)ws;
  _Float16* h_pk  = (_Float16*)(ws + OFF_HPK);
  int*      flags = (int*)(ws + OFF_FLAGS);
  _Float16* Upk   = (_Float16*)(ws + OFF_UPK);
  _Float16* Wpk   = (_Float16*)(ws + OFF_WPK);

  convert_x_kernel<<<4096, 256, 0, stream>>>((const float*)d_in[0], x16);

  PackParams pp;
  for (int g = 0; g < 8; ++g) {
    pp.W[g] = (const float*)d_in[1 + g];
    pp.U[g] = (const float*)d_in[9 + g];
  }
  pp.Upk = Upk; pp.Wpk = Wpk;
  pack_frags_kernel<<<16384, 256, 0, stream>>>(pp);

  zero_kernel<<<4, 256, 0, stream>>>(flags);   // 1024 ints = flag ring

  ScanParams p;
  for (int g = 0; g < 8; ++g) p.bias[g] = (const float*)d_in[17 + g];
  p.x16 = x16; p.h_pk = h_pk; p.flags = flags;
  p.Upk = Upk; p.Wpk = Wpk; p.out = (float*)d_out;

  void* args[] = { (void*)&p };
  hipLaunchCooperativeKernel((const void*)lstm_scan_kernel, dim3(128), dim3(256),
                             args, 0, stream);

  add_bwd_kernel<<<4096, 256, 0, stream>>>(h_pk, (float*)d_out);
}